// Round 11
// baseline (1140.904 us; speedup 1.0000x reference)
//
#include <hip/hip_runtime.h>

// Dynamic range compressor via hierarchically composed max-affine scan ops.
//   gr[t]  = max(20*log10(|x|+1e-8) - thr, 0)*(1-1/ratio)
//   g[0]=0; g[t] = (1-a)*g[t-1] + a*gr[t],  a = att if gr[t]>g[t-1] else rel
//   out[t] = sign(x)*(|x|+1e-8)*10^((mk - g[t])/20)
// m-fold composition of the per-sample max-affine update is max-affine with
// slope ladder b1^(m-k)b2^k. Round 11 (after r10's asm-ring crash + r7's
// VGPR=56 spill evidence): NO asm, NO deep per-thread pipelines. Accuracy:
// 65-piece ops everywhere (r8/r9 calibrated 33-piece final ladder q^16 prune
// error ~0.03; q^8 spacing => ~0.007, total ~0.015 < 0.0308 threshold).
//   pre64: exact 65-piece 64-sample ops (r7-validated algebra + 1 level)
//   mid x3: 65∘65 -> 129 -> keep-even -> 65 (spans 128/256/512)
//   scanA: per chunk, 16 applies of L2-resident ops512 (4.7 MB) -> g_start
//   scanB: per chunk, 512-sample output region (2-dep chain/sample)
// NOTE: no <math.h> (glibc __MATHCALL collides with HIP intrinsics).

#define T_LEN   (1 << 20)
#define C_CHUNK 512

typedef _Float16 half_t;
typedef _Float16 half8 __attribute__((ext_vector_type(8)));
typedef float    fvec4 __attribute__((ext_vector_type(4)));

__device__ __forceinline__ float fmax3f(float a, float b, float c) {
  return fmaxf(fmaxf(a, b), c);
}

// dst = hi ∘ lo (hi applied after lo). Piece index = release count.
// shi[i] = slope of hi's piece i. Exact.
template <int P, int Q>
__device__ __forceinline__ void compose(float* __restrict__ dst,
                                        const float* __restrict__ hi,
                                        const float* __restrict__ lo,
                                        const float* __restrict__ shi) {
#pragma unroll
  for (int k = 0; k < P + Q - 1; ++k) {
    float m = -1e30f;
#pragma unroll
    for (int i = 0; i < P; ++i) {
      const int j = k - i;
      if (j >= 0 && j < Q) m = fmaxf(m, fmaf(shi[i], lo[j], hi[i]));
    }
    dst[k] = m;
  }
}

// One thread per 64-sample record: gr -> quads -> 9 -> 17 -> 33 -> EXACT 65.
// Store 65 fp16 intercepts in 9 half8 (144 B).
__global__ __launch_bounds__(64) void pre64_kernel(
    const float* __restrict__ audio,
    const float* __restrict__ p_thr,
    const float* __restrict__ p_ratio,
    const float* __restrict__ p_att,
    const float* __restrict__ p_rel,
    half8* __restrict__ ops64, int nrec) {
  const int rec = blockIdx.x * 64 + (int)threadIdx.x;
  if (rec >= nrec) return;
  const float thr = p_thr[0];
  const float r1  = 1.0f - 1.0f / p_ratio[0];
  const float K   = 6.0205999132796239f * r1;    // 20*log10(2)*r1
  const float Cc  = -thr * r1;
  const float L2E = 1.4426950408889634f;
  const float aatt = 1.0f - __builtin_exp2f(-L2E / (p_att[0] * 48000.0f));
  const float arel = 1.0f - __builtin_exp2f(-L2E / (p_rel[0] * 48000.0f));
  const float b1 = 1.0f - aatt, b2 = 1.0f - arel;
  const float s0 = b1 * b1, s1 = b1 * b2, s2 = b2 * b2;
  const float rat = b2 / b1;

  float s4[5], s8[9], s16[17], s32[33];
  {
    const float b1_2 = b1 * b1, b1_4 = b1_2 * b1_2, b1_8 = b1_4 * b1_4;
    const float b1_16 = b1_8 * b1_8, b1_32 = b1_16 * b1_16;
    float p = b1_4;
#pragma unroll
    for (int i = 0; i < 5; ++i) { s4[i] = p; p *= rat; }
    p = b1_8;
#pragma unroll
    for (int i = 0; i < 9; ++i) { s8[i] = p; p *= rat; }
    p = b1_16;
#pragma unroll
    for (int i = 0; i < 17; ++i) { s16[i] = p; p *= rat; }
    p = b1_32;
#pragma unroll
    for (int i = 0; i < 33; ++i) { s32[i] = p; p *= rat; }
  }

  const fvec4* A4 = (const fvec4*)(audio) + (size_t)rec * 16;
  const bool zf = ((rec & (T_LEN / 64 - 1)) == 0);

  float q[16][5];
#pragma unroll
  for (int b = 0; b < 16; ++b) {
    fvec4 v = A4[b];
    float gg[4];
#pragma unroll
    for (int j = 0; j < 4; ++j)
      gg[j] = fmaxf(fmaf(K, __builtin_log2f(fabsf(v[j]) + 1e-8f), Cc), 0.0f);
    if (zf && b == 0) gg[0] = 0.0f;   // t==0: reference makes no update
    float A0 = aatt * gg[0], R0 = arel * gg[0];
    float A1 = aatt * gg[1], R1 = arel * gg[1];
    float u0 = fmaf(b1, A0, A1);
    float um = fmaxf(fmaf(b1, R0, A1), fmaf(b2, A0, R1));
    float u2 = fmaf(b2, R0, R1);
    float A2 = aatt * gg[2], R2 = arel * gg[2];
    float A3 = aatt * gg[3], R3 = arel * gg[3];
    float v0 = fmaf(b1, A2, A3);
    float vm = fmaxf(fmaf(b1, R2, A3), fmaf(b2, A2, R3));
    float v2 = fmaf(b2, R2, R3);
    q[b][0] = fmaf(s0, u0, v0);
    q[b][1] = fmaxf(fmaf(s0, um, v0), fmaf(s1, u0, vm));
    q[b][2] = fmax3f(fmaf(s0, u2, v0), fmaf(s1, um, vm), fmaf(s2, u0, v2));
    q[b][3] = fmaxf(fmaf(s1, u2, vm), fmaf(s2, um, v2));
    q[b][4] = fmaf(s2, u2, v2);
  }

  float o9[8][9];
#pragma unroll
  for (int t = 0; t < 8; ++t) compose<5, 5>(o9[t], q[2*t+1], q[2*t], s4);
  float o17[4][17];
#pragma unroll
  for (int t = 0; t < 4; ++t) compose<9, 9>(o17[t], o9[2*t+1], o9[2*t], s8);
  float o33[2][33];
#pragma unroll
  for (int t = 0; t < 2; ++t) compose<17, 17>(o33[t], o17[2*t+1], o17[2*t], s16);
  float o65[65];
  compose<33, 33>(o65, o33[1], o33[0], s32);   // EXACT 65-piece 64-sample op

  half8* dst = ops64 + (size_t)rec * 9;
#pragma unroll
  for (int j8 = 0; j8 < 9; ++j8) {
    half8 hb;
#pragma unroll
    for (int e = 0; e < 8; ++e) {
      const int k = 8 * j8 + e;
      hb[e] = (k < 65) ? (half_t)o65[k] : (half_t)0.0f;
    }
    dst[j8] = hb;
  }
}

// dst[idx] = src[2idx+1] ∘ src[2idx], 129 -> keep even -> 65.
// Child slopes: b1^(64*EC) * (q^EC)^i, EC = 1<<LOG2EC.
template <int LOG2EC>
__global__ __launch_bounds__(64) void mid_kernel(
    const half8* __restrict__ src,
    half8* __restrict__ dst,
    const float* __restrict__ p_att,
    const float* __restrict__ p_rel, int ndst) {
  const int idx = blockIdx.x * 64 + (int)threadIdx.x;
  if (idx >= ndst) return;
  const float L2E = 1.4426950408889634f;
  const float aatt = 1.0f - __builtin_exp2f(-L2E / (p_att[0] * 48000.0f));
  const float arel = 1.0f - __builtin_exp2f(-L2E / (p_rel[0] * 48000.0f));
  const float b1 = 1.0f - aatt, b2 = 1.0f - arel;
  const float b1_2 = b1 * b1, b1_4 = b1_2 * b1_2, b1_8 = b1_4 * b1_4;
  const float b1_16 = b1_8 * b1_8, b1_32 = b1_16 * b1_16;
  float bM = b1_32 * b1_32;       // b1^64
  float qE = b2 / b1;
#pragma unroll
  for (int s = 0; s < LOG2EC; ++s) { bM *= bM; qE *= qE; }

  float lad[65];
  {
    float p = bM;
#pragma unroll
    for (int i = 0; i < 65; ++i) { lad[i] = p; p *= qE; }
  }

  float lo[65], hi[65];
  const half8* pl = src + (size_t)(2 * idx) * 9;
#pragma unroll
  for (int j8 = 0; j8 < 9; ++j8) {
    half8 a = pl[j8], b = pl[9 + j8];
#pragma unroll
    for (int e = 0; e < 8; ++e) {
      const int k = 8 * j8 + e;
      if (k < 65) { lo[k] = (float)a[e]; hi[k] = (float)b[e]; }
    }
  }

  float o[65];
#pragma unroll
  for (int kk = 0; kk < 65; ++kk) {
    const int Kk = 2 * kk;
    float m = -1e30f;
#pragma unroll
    for (int i = 0; i < 65; ++i) {
      const int j = Kk - i;
      if (j >= 0 && j < 65) m = fmaxf(m, fmaf(lad[i], lo[j], hi[i]));
    }
    o[kk] = m;
  }

  half8* d8 = dst + (size_t)idx * 9;
#pragma unroll
  for (int j8 = 0; j8 < 9; ++j8) {
    half8 hb;
#pragma unroll
    for (int e = 0; e < 8; ++e) {
      const int k = 8 * j8 + e;
      hb[e] = (k < 65) ? (half_t)o[k] : (half_t)0.0f;
    }
    d8[j8] = hb;
  }
}

// Per chunk: apply up to 16 ops512 (65-piece, L2-resident) from g=0.
__global__ __launch_bounds__(64) void scanA_kernel(
    const half8* __restrict__ ops512,
    const float* __restrict__ p_att,
    const float* __restrict__ p_rel,
    float* __restrict__ g_start, int nchunks) {
  const int tid = blockIdx.x * 64 + (int)threadIdx.x;
  if (tid >= nchunks) return;
  const int ch = tid >> 11;            // 2048 chunks/channel
  const int c  = tid & 2047;
  const float L2E = 1.4426950408889634f;
  const float aatt = 1.0f - __builtin_exp2f(-L2E / (p_att[0] * 48000.0f));
  const float arel = 1.0f - __builtin_exp2f(-L2E / (p_rel[0] * 48000.0f));
  const float b1 = 1.0f - aatt, b2 = 1.0f - arel;

  float S[65];   // b1^512 * q^(8i)
  {
    float qq = b2 / b1;
    qq *= qq; qq *= qq; qq *= qq;                       // q^8
    const float b1_2 = b1 * b1, b1_4 = b1_2 * b1_2, b1_8 = b1_4 * b1_4;
    const float b1_16 = b1_8 * b1_8, b1_32 = b1_16 * b1_16;
    const float b1_64 = b1_32 * b1_32, b1_128 = b1_64 * b1_64;
    const float b1_256 = b1_128 * b1_128;
    float p = b1_256 * b1_256;                          // b1^512
#pragma unroll
    for (int i = 0; i < 65; ++i) { S[i] = p; p *= qq; }
  }

  const int nops = (c < 16) ? c : 16;
  const half8* P = ops512 + (size_t)(ch * 2048 + c - nops) * 9;

  float g = 0.0f;
#pragma unroll 1
  for (int r = 0; r < nops; ++r) {
    half8 o[9];
#pragma unroll
    for (int i = 0; i < 9; ++i) o[i] = P[9 * r + i];
    float m0 = -1e30f, m1 = -1e30f, m2 = -1e30f, m3 = -1e30f;
#pragma unroll
    for (int i = 0; i < 65; ++i) {
      const float t = fmaf(S[i], g, (float)o[i >> 3][i & 7]);
      if ((i & 3) == 0) m0 = fmaxf(m0, t);
      else if ((i & 3) == 1) m1 = fmaxf(m1, t);
      else if ((i & 3) == 2) m2 = fmaxf(m2, t);
      else m3 = fmaxf(m3, t);
    }
    g = fmaxf(fmaxf(m0, m1), fmaxf(m2, m3));
  }
  g_start[tid] = g;
}

// Per chunk: 512-sample output recurrence from g_start.
__global__ __launch_bounds__(64) void scanB_kernel(
    const float* __restrict__ audio,
    const float* __restrict__ g_start,
    const float* __restrict__ p_thr,
    const float* __restrict__ p_ratio,
    const float* __restrict__ p_att,
    const float* __restrict__ p_rel,
    const float* __restrict__ p_mk,
    float* __restrict__ out, int nchunks) {
  const int tid = blockIdx.x * 64 + (int)threadIdx.x;
  if (tid >= nchunks) return;
  const int ch = tid >> 11;
  const int t0 = (tid & 2047) * C_CHUNK;

  const float thr = p_thr[0];
  const float r1  = 1.0f - 1.0f / p_ratio[0];
  const float K   = 6.0205999132796239f * r1;
  const float Cc  = -thr * r1;
  const float L2E = 1.4426950408889634f;
  const float aatt = 1.0f - __builtin_exp2f(-L2E / (p_att[0] * 48000.0f));
  const float arel = 1.0f - __builtin_exp2f(-L2E / (p_rel[0] * 48000.0f));
  const float b1 = 1.0f - aatt, b2 = 1.0f - arel;
  const float EK  = 0.16609640474436813f;         // log2(10)/20
  const float emk = p_mk[0] * EK;

  float g = g_start[tid];
  const fvec4* Ap = (const fvec4*)(audio + (size_t)ch * T_LEN + t0);
  fvec4* Op = (fvec4*)(out + (size_t)ch * T_LEN + t0);
  const bool zfix = (t0 == 0);

  fvec4 a0[8], a1[8];
  auto lda = [&](fvec4 (&ab)[8], int b) {
#pragma unroll
    for (int i = 0; i < 8; ++i) ab[i] = Ap[8 * b + i];
  };
  auto emit = [&](const fvec4 (&ab)[8], int b, bool first) {
    fvec4 r[8];
#pragma unroll
    for (int s = 0; s < 32; ++s) {
      float x = ab[s >> 2][s & 3];
      float ax = fabsf(x) + 1e-8f;
      float grv = fmaxf(fmaf(K, __builtin_log2f(ax), Cc), 0.0f);
      if (first && s == 0 && zfix) grv = 0.0f;   // t==0: g stays 0
      float Aa = aatt * grv, Rr = arel * grv;    // off-chain
      g = fmaxf(fmaf(b1, g, Aa), fmaf(b2, g, Rr));   // 2-dep chain
      float mag = ax * __builtin_exp2f(fmaf(-EK, g, emk));
      float o = copysignf(mag, x);
      r[s >> 2][s & 3] = (x == 0.0f) ? 0.0f : o;
    }
#pragma unroll
    for (int i = 0; i < 8; ++i) Op[8 * b + i] = r[i];
  };

  const int NB = C_CHUNK / 32;   // 16
  lda(a0, 0);
#pragma unroll 1
  for (int b = 0; b < NB; b += 2) {
    lda(a1, b + 1);
    emit(a0, b, b == 0);
    const int bnx = (b + 2 < NB) ? b + 2 : NB - 1;
    lda(a0, bnx);
    emit(a1, b + 1, false);
  }
}

extern "C" void kernel_launch(void* const* d_in, const int* in_sizes, int n_in,
                              void* d_out, int out_size, void* d_ws, size_t ws_size,
                              hipStream_t stream) {
  const float* audio   = (const float*)d_in[0];
  const float* p_thr   = (const float*)d_in[1];
  const float* p_ratio = (const float*)d_in[2];
  const float* p_att   = (const float*)d_in[3];
  const float* p_rel   = (const float*)d_in[4];
  const float* p_mk    = (const float*)d_in[5];
  float* outp = (float*)d_out;

  const int n = in_sizes[0];           // 16 * 2^20
  const int n64  = n / 64;             // 262144 * 144 B = 37.75 MB
  const int n128 = n / 128;            // 131072 * 144 B = 18.87 MB
  const int n256 = n / 256;            //  65536 * 144 B =  9.44 MB
  const int n512 = n / 512;            //  32768 * 144 B =  4.72 MB
  const int nchunks = n / C_CHUNK;     // 32768

  // ws layout (ws_size >= 67,108,864 proven in r2/r3):
  half8* ops64  = (half8*)d_ws;                              // [0, 37748736)
  half8* ops128 = (half8*)((char*)d_ws + 37748736);          // [37.75, 56.62 MB)
  half8* ops256 = (half8*)((char*)d_ws + 56623104);          // [56.62, 66.06 MB)
  half8* ops512 = (half8*)d_ws;                              // [0, 4.72 MB) ops64 dead
  float* g_start = (float*)((char*)d_ws + 8388608);          // [8 MB, +128 KB)

  pre64_kernel<<<n64 / 64, 64, 0, stream>>>(
      audio, p_thr, p_ratio, p_att, p_rel, ops64, n64);
  mid_kernel<0><<<n128 / 64, 64, 0, stream>>>(ops64,  ops128, p_att, p_rel, n128);
  mid_kernel<1><<<n256 / 64, 64, 0, stream>>>(ops128, ops256, p_att, p_rel, n256);
  mid_kernel<2><<<n512 / 64, 64, 0, stream>>>(ops256, ops512, p_att, p_rel, n512);
  scanA_kernel<<<nchunks / 64, 64, 0, stream>>>(
      ops512, p_att, p_rel, g_start, nchunks);
  scanB_kernel<<<nchunks / 64, 64, 0, stream>>>(
      audio, g_start, p_thr, p_ratio, p_att, p_rel, p_mk, outp, nchunks);
}

// Round 12
// 202.717 us; speedup vs baseline: 5.6281x; 5.6281x over previous
//
#include <hip/hip_runtime.h>

// Dynamic range compressor via EXACT composed max-affine scan operators.
//   gr[t]  = max(20*log10(|x|+1e-8) - thr, 0)*(1-1/ratio)
//   g[0]=0; g[t] = (1-a)*g[t-1] + a*gr[t],  a = att if gr[t]>g[t-1] else rel
//   out[t] = sign(x)*(|x|+1e-8)*10^((mk - g[t])/20)
// m-fold composition of the per-sample update is EXACTLY max-affine with
// slope ladder b1^(m-k)b2^k (adjacent ratio q=b2/b1). No pruning (exact path
// has measured at the bf16 floor in r5/r7/r11).
// Round 12 (r11: mid_kernel 374us from 260-float scratch spill, VGPR=68):
//   - NO mid levels: scanA applies 64-sample 65-piece ops directly
//     (128 applies, ~195 VALU each covers L2 latency; simple C ping-pong).
//   - i-major compose with incremental slope scalar (no slope tables).
//   - pre64 tree evaluated depth-first (peak live ~131 floats).
//   - ops stored TRANSPOSED [p][ch]; scanA lanes ch-major -> 16 consecutive
//     144B records per lane-group (fixes every prior comp kernel's scatter).
// NOTE: no <math.h> (glibc __MATHCALL collides with HIP intrinsics).

#define T_LEN   (1 << 20)
#define NCH     16
#define C_CHUNK 512
#define RECS_PER_CH (T_LEN / 64)     // 16384 64-sample ops per channel
#define CH_CHUNKS   (T_LEN / C_CHUNK) // 2048 chunks per channel
#define N_WARM_OPS  128               // W = 8192 samples

typedef _Float16 half_t;
typedef _Float16 half8 __attribute__((ext_vector_type(8)));
typedef float    fvec4 __attribute__((ext_vector_type(4)));

__device__ __forceinline__ float fmax3f(float a, float b, float c) {
  return fmaxf(fmaxf(a, b), c);
}

// dst = hi ∘ lo (hi after lo), i-major, slope updated incrementally.
// s = slope of hi piece 0 (= b1^span), rat = q. Exact; no tables.
template <int P, int Q>
__device__ __forceinline__ void compose_im(float* __restrict__ dst,
                                           const float* __restrict__ hi,
                                           const float* __restrict__ lo,
                                           float s, float rat) {
#pragma unroll
  for (int k = 0; k < P + Q - 1; ++k) dst[k] = -1e30f;
#pragma unroll
  for (int i = 0; i < P; ++i) {
#pragma unroll
    for (int j = 0; j < Q; ++j)
      dst[i + j] = fmaxf(dst[i + j], fmaf(s, lo[j], hi[i]));
    s *= rat;
  }
}

// One thread per 64-sample record: depth-first tree -> EXACT 65-piece op.
// Write 9 half8 (144 B) at TRANSPOSED index p*16+ch.
__global__ __launch_bounds__(256) void pre64_kernel(
    const float* __restrict__ audio,
    const float* __restrict__ p_thr,
    const float* __restrict__ p_ratio,
    const float* __restrict__ p_att,
    const float* __restrict__ p_rel,
    half8* __restrict__ ops64, int nrec) {
  const int rec = blockIdx.x * 256 + (int)threadIdx.x;
  if (rec >= nrec) return;
  const int ch = rec >> 14;            // RECS_PER_CH = 16384
  const int p  = rec & 16383;

  const float thr = p_thr[0];
  const float r1  = 1.0f - 1.0f / p_ratio[0];
  const float K   = 6.0205999132796239f * r1;    // 20*log10(2)*r1
  const float Cc  = -thr * r1;
  const float L2E = 1.4426950408889634f;
  const float aatt = 1.0f - __builtin_exp2f(-L2E / (p_att[0] * 48000.0f));
  const float arel = 1.0f - __builtin_exp2f(-L2E / (p_rel[0] * 48000.0f));
  const float b1 = 1.0f - aatt, b2 = 1.0f - arel;
  const float s0 = b1 * b1, s1 = b1 * b2, s2 = b2 * b2;
  const float rat = b2 / b1;
  const float b1_4 = s0 * s0, b1_8 = b1_4 * b1_4, b1_16 = b1_8 * b1_8,
              b1_32 = b1_16 * b1_16;

  const fvec4* A4 = (const fvec4*)(audio) + (size_t)rec * 16;
  const bool zf = (p == 0);

  auto mkquad = [&](int b, float* qq) {
    fvec4 v = A4[b];
    float gg[4];
#pragma unroll
    for (int j = 0; j < 4; ++j)
      gg[j] = fmaxf(fmaf(K, __builtin_log2f(fabsf(v[j]) + 1e-8f), Cc), 0.0f);
    if (zf && b == 0) gg[0] = 0.0f;    // t==0: reference makes no update
    float A0 = aatt * gg[0], R0 = arel * gg[0];
    float A1 = aatt * gg[1], R1 = arel * gg[1];
    float u0 = fmaf(b1, A0, A1);
    float um = fmaxf(fmaf(b1, R0, A1), fmaf(b2, A0, R1));
    float u2 = fmaf(b2, R0, R1);
    float A2 = aatt * gg[2], R2 = arel * gg[2];
    float A3 = aatt * gg[3], R3 = arel * gg[3];
    float v0 = fmaf(b1, A2, A3);
    float vm = fmaxf(fmaf(b1, R2, A3), fmaf(b2, A2, R3));
    float v2 = fmaf(b2, R2, R3);
    qq[0] = fmaf(s0, u0, v0);
    qq[1] = fmaxf(fmaf(s0, um, v0), fmaf(s1, u0, vm));
    qq[2] = fmax3f(fmaf(s0, u2, v0), fmaf(s1, um, vm), fmaf(s2, u0, v2));
    qq[3] = fmaxf(fmaf(s1, u2, vm), fmaf(s2, um, v2));
    qq[4] = fmaf(s2, u2, v2);
  };
  auto mk17 = [&](int qb, float* o17) {   // 4 quads -> 17-piece span-16 op
    float qa[5], qc[5], o9a[9], o9b[9];
    mkquad(qb + 0, qa); mkquad(qb + 1, qc);
    compose_im<5, 5>(o9a, qc, qa, b1_4, rat);
    mkquad(qb + 2, qa); mkquad(qb + 3, qc);
    compose_im<5, 5>(o9b, qc, qa, b1_4, rat);
    compose_im<9, 9>(o17, o9b, o9a, b1_8, rat);
  };

  float o33a[33], o33b[33], o65[65];
  {
    float o17a[17], o17b[17];
    mk17(0, o17a); mk17(4, o17b);
    compose_im<17, 17>(o33a, o17b, o17a, b1_16, rat);
    mk17(8, o17a); mk17(12, o17b);
    compose_im<17, 17>(o33b, o17b, o17a, b1_16, rat);
  }
  compose_im<33, 33>(o65, o33b, o33a, b1_32, rat);   // EXACT span-64 op

  half8* dst = ops64 + (size_t)(p * NCH + ch) * 9;
#pragma unroll
  for (int j8 = 0; j8 < 9; ++j8) {
    half8 hb;
#pragma unroll
    for (int e = 0; e < 8; ++e) {
      const int k = 8 * j8 + e;
      hb[e] = (k < 65) ? (half_t)o65[k] : (half_t)0.0f;
    }
    dst[j8] = hb;
  }
}

// Warm-up scan: lane l -> (ch = l&15, cpos = wave*4 + l>>4). Applies up to
// 128 span-64 ops (exact 65-piece) ending at the chunk start; writes g_start.
__global__ __launch_bounds__(256) void scanA_kernel(
    const half8* __restrict__ ops64,
    const float* __restrict__ p_att,
    const float* __restrict__ p_rel,
    float* __restrict__ g_start, int nthreads) {
  const int tid = blockIdx.x * 256 + (int)threadIdx.x;
  if (tid >= nthreads) return;
  const int l    = tid & 63;
  const int wv   = tid >> 6;
  const int ch   = l & 15;
  const int cpos = wv * 4 + (l >> 4);        // 0..2047

  const float L2E = 1.4426950408889634f;
  const float aatt = 1.0f - __builtin_exp2f(-L2E / (p_att[0] * 48000.0f));
  const float arel = 1.0f - __builtin_exp2f(-L2E / (p_rel[0] * 48000.0f));
  const float b1 = 1.0f - aatt, b2 = 1.0f - arel;
  const float rat = b2 / b1;

  float S[65];   // b1^(64-i) b2^i
  {
    const float b1_2 = b1 * b1, b1_4 = b1_2 * b1_2, b1_8 = b1_4 * b1_4;
    const float b1_16 = b1_8 * b1_8, b1_32 = b1_16 * b1_16;
    float pw = b1_32 * b1_32;   // b1^64
#pragma unroll
    for (int i = 0; i < 65; ++i) { S[i] = pw; pw *= rat; }
  }

  float g = 0.0f;
  auto apply = [&](const half8 (&o)[9]) {
    float m0 = -1e30f, m1 = -1e30f, m2 = -1e30f, m3 = -1e30f;
#pragma unroll
    for (int i = 0; i < 65; ++i) {
      const float t = fmaf(S[i], g, (float)o[i >> 3][i & 7]);
      if ((i & 3) == 0) m0 = fmaxf(m0, t);
      else if ((i & 3) == 1) m1 = fmaxf(m1, t);
      else if ((i & 3) == 2) m2 = fmaxf(m2, t);
      else m3 = fmaxf(m3, t);
    }
    g = fmaxf(fmaxf(m0, m1), fmaxf(m2, m3));
  };

  const int navail = cpos * 8;
  const int nops = (navail < N_WARM_OPS) ? navail : N_WARM_OPS;  // even
  if (nops > 0) {
    const int p0 = cpos * 8 - nops;
    const half8* P = ops64 + (size_t)(p0 * NCH + ch) * 9;
    const size_t stride = (size_t)NCH * 9;    // one op position
    half8 bA[9], bB[9];
#pragma unroll
    for (int i = 0; i < 9; ++i) bA[i] = P[i];
#pragma unroll 1
    for (int r = 0; r + 2 <= nops; r += 2) {
      const half8* Pn = P + (size_t)(r + 1) * stride;
#pragma unroll
      for (int i = 0; i < 9; ++i) bB[i] = Pn[i];
      apply(bA);
      // r+2 == nops loads the op at the chunk start: in-bounds, unused.
      const half8* Pn2 = P + (size_t)(r + 2) * stride;
#pragma unroll
      for (int i = 0; i < 9; ++i) bA[i] = Pn2[i];
      apply(bB);
    }
  }
  g_start[ch * CH_CHUNKS + cpos] = g;
}

// Output region: per chunk, 512-sample recurrence from g_start.
__global__ __launch_bounds__(256) void scanB_kernel(
    const float* __restrict__ audio,
    const float* __restrict__ g_start,
    const float* __restrict__ p_thr,
    const float* __restrict__ p_ratio,
    const float* __restrict__ p_att,
    const float* __restrict__ p_rel,
    const float* __restrict__ p_mk,
    float* __restrict__ out, int nchunks) {
  const int tid = blockIdx.x * 256 + (int)threadIdx.x;
  if (tid >= nchunks) return;
  const int ch = tid >> 11;
  const int t0 = (tid & 2047) * C_CHUNK;

  const float thr = p_thr[0];
  const float r1  = 1.0f - 1.0f / p_ratio[0];
  const float K   = 6.0205999132796239f * r1;
  const float Cc  = -thr * r1;
  const float L2E = 1.4426950408889634f;
  const float aatt = 1.0f - __builtin_exp2f(-L2E / (p_att[0] * 48000.0f));
  const float arel = 1.0f - __builtin_exp2f(-L2E / (p_rel[0] * 48000.0f));
  const float b1 = 1.0f - aatt, b2 = 1.0f - arel;
  const float EK  = 0.16609640474436813f;         // log2(10)/20
  const float emk = p_mk[0] * EK;

  float g = g_start[tid];
  const fvec4* Ap = (const fvec4*)(audio + (size_t)ch * T_LEN + t0);
  fvec4* Op = (fvec4*)(out + (size_t)ch * T_LEN + t0);
  const bool zfix = (t0 == 0);

  fvec4 a0[8], a1[8];
  auto lda = [&](fvec4 (&ab)[8], int b) {
#pragma unroll
    for (int i = 0; i < 8; ++i) ab[i] = Ap[8 * b + i];
  };
  auto emit = [&](const fvec4 (&ab)[8], int b, bool first) {
    fvec4 r[8];
#pragma unroll
    for (int s = 0; s < 32; ++s) {
      float x = ab[s >> 2][s & 3];
      float ax = fabsf(x) + 1e-8f;
      float grv = fmaxf(fmaf(K, __builtin_log2f(ax), Cc), 0.0f);
      if (first && s == 0 && zfix) grv = 0.0f;   // t==0: g stays 0
      float Aa = aatt * grv, Rr = arel * grv;    // off-chain
      g = fmaxf(fmaf(b1, g, Aa), fmaf(b2, g, Rr));   // 2-dep chain
      float mag = ax * __builtin_exp2f(fmaf(-EK, g, emk));
      float o = copysignf(mag, x);
      r[s >> 2][s & 3] = (x == 0.0f) ? 0.0f : o;
    }
#pragma unroll
    for (int i = 0; i < 8; ++i) Op[8 * b + i] = r[i];
  };

  const int NB = C_CHUNK / 32;   // 16
  lda(a0, 0);
#pragma unroll 1
  for (int b = 0; b < NB; b += 2) {
    lda(a1, b + 1);
    emit(a0, b, b == 0);
    const int bnx = (b + 2 < NB) ? b + 2 : NB - 1;
    lda(a0, bnx);
    emit(a1, b + 1, false);
  }
}

extern "C" void kernel_launch(void* const* d_in, const int* in_sizes, int n_in,
                              void* d_out, int out_size, void* d_ws, size_t ws_size,
                              hipStream_t stream) {
  const float* audio   = (const float*)d_in[0];
  const float* p_thr   = (const float*)d_in[1];
  const float* p_ratio = (const float*)d_in[2];
  const float* p_att   = (const float*)d_in[3];
  const float* p_rel   = (const float*)d_in[4];
  const float* p_mk    = (const float*)d_in[5];
  float* outp = (float*)d_out;

  const int n = in_sizes[0];           // 16 * 2^20
  const int nrec = n / 64;             // 262144 ops * 144 B = 37.75 MB
  const int nchunks = n / C_CHUNK;     // 32768

  half8* ops64   = (half8*)d_ws;                        // [0, 37.75 MB)
  float* g_start = (float*)((char*)d_ws + ((size_t)48 << 20));  // 128 KB

  pre64_kernel<<<(nrec + 255) / 256, 256, 0, stream>>>(
      audio, p_thr, p_ratio, p_att, p_rel, ops64, nrec);
  scanA_kernel<<<(nchunks + 255) / 256, 256, 0, stream>>>(
      ops64, p_att, p_rel, g_start, nchunks);
  scanB_kernel<<<(nchunks + 255) / 256, 256, 0, stream>>>(
      audio, g_start, p_thr, p_ratio, p_att, p_rel, p_mk, outp, nchunks);
}

// Round 13
// 180.125 us; speedup vs baseline: 6.3340x; 1.1254x over previous
//
#include <hip/hip_runtime.h>

// Dynamic range compressor via EXACT composed max-affine scan operators.
//   gr[t]  = max(20*log10(|x|+1e-8) - thr, 0)*(1-1/ratio)
//   g[0]=0; g[t] = (1-a)*g[t-1] + a*gr[t],  a = att if gr[t]>g[t-1] else rel
//   out[t] = sign(x)*(|x|+1e-8)*10^((mk - g[t])/20)
// 64-fold composition of the per-sample update = EXACT 65-piece max-affine
// op, slopes b1^(64-i)b2^i. Pipeline: pre64 (exact span-64 ops, fp16 144B,
// layout [p][ch]) -> scanA (128 applies -> g_start) -> scanB (512-sample
// output region).
// Round 13 (r12: scanA VGPR=64 proved S[65]+buffers in SCRATCH, 2050
// cyc/apply): hipcc dumps large C arrays to scratch under its occupancy
// heuristic regardless of static indexing (4th recurrence: r7/r10/r11/r12).
// Fix: NO hot arrays — S as 8 named f32x8 ext-vector SSA values + scalar,
// op buffers as named half8 registers, vectorized apply; __launch_bounds__
// (64,1) to raise the RA budget; XCD-chunked wg swizzle for op-window L2
// sharing. pre64 gets (256,1) only; scanB unchanged.
// NOTE: no <math.h> (glibc __MATHCALL collides with HIP intrinsics).

#define T_LEN   (1 << 20)
#define NCH     16
#define C_CHUNK 512
#define RECS_PER_CH (T_LEN / 64)      // 16384 span-64 ops per channel
#define CH_CHUNKS   (T_LEN / C_CHUNK) // 2048 chunks per channel
#define N_WARM_OPS  128               // W = 8192 samples

typedef _Float16 half_t;
typedef _Float16 half8 __attribute__((ext_vector_type(8)));
typedef float    fvec4 __attribute__((ext_vector_type(4)));
typedef float    f32x8 __attribute__((ext_vector_type(8)));

__device__ __forceinline__ float fmax3f(float a, float b, float c) {
  return fmaxf(fmaxf(a, b), c);
}

// dst = hi ∘ lo (hi after lo), i-major, slope updated incrementally. Exact.
template <int P, int Q>
__device__ __forceinline__ void compose_im(float* __restrict__ dst,
                                           const float* __restrict__ hi,
                                           const float* __restrict__ lo,
                                           float s, float rat) {
#pragma unroll
  for (int k = 0; k < P + Q - 1; ++k) dst[k] = -1e30f;
#pragma unroll
  for (int i = 0; i < P; ++i) {
#pragma unroll
    for (int j = 0; j < Q; ++j)
      dst[i + j] = fmaxf(dst[i + j], fmaf(s, lo[j], hi[i]));
    s *= rat;
  }
}

// One thread per 64-sample record: depth-first tree -> EXACT 65-piece op.
// Write 9 half8 (144 B) at TRANSPOSED index p*16+ch.
__global__ __launch_bounds__(256, 1) void pre64_kernel(
    const float* __restrict__ audio,
    const float* __restrict__ p_thr,
    const float* __restrict__ p_ratio,
    const float* __restrict__ p_att,
    const float* __restrict__ p_rel,
    half8* __restrict__ ops64, int nrec) {
  const int rec = blockIdx.x * 256 + (int)threadIdx.x;
  if (rec >= nrec) return;
  const int ch = rec >> 14;            // RECS_PER_CH = 16384
  const int p  = rec & 16383;

  const float thr = p_thr[0];
  const float r1  = 1.0f - 1.0f / p_ratio[0];
  const float K   = 6.0205999132796239f * r1;    // 20*log10(2)*r1
  const float Cc  = -thr * r1;
  const float L2E = 1.4426950408889634f;
  const float aatt = 1.0f - __builtin_exp2f(-L2E / (p_att[0] * 48000.0f));
  const float arel = 1.0f - __builtin_exp2f(-L2E / (p_rel[0] * 48000.0f));
  const float b1 = 1.0f - aatt, b2 = 1.0f - arel;
  const float s0 = b1 * b1, s1 = b1 * b2, s2 = b2 * b2;
  const float rat = b2 / b1;
  const float b1_4 = s0 * s0, b1_8 = b1_4 * b1_4, b1_16 = b1_8 * b1_8,
              b1_32 = b1_16 * b1_16;

  const fvec4* A4 = (const fvec4*)(audio) + (size_t)rec * 16;
  const bool zf = (p == 0);

  auto mkquad = [&](int b, float* qq) {
    fvec4 v = A4[b];
    float gg[4];
#pragma unroll
    for (int j = 0; j < 4; ++j)
      gg[j] = fmaxf(fmaf(K, __builtin_log2f(fabsf(v[j]) + 1e-8f), Cc), 0.0f);
    if (zf && b == 0) gg[0] = 0.0f;    // t==0: reference makes no update
    float A0 = aatt * gg[0], R0 = arel * gg[0];
    float A1 = aatt * gg[1], R1 = arel * gg[1];
    float u0 = fmaf(b1, A0, A1);
    float um = fmaxf(fmaf(b1, R0, A1), fmaf(b2, A0, R1));
    float u2 = fmaf(b2, R0, R1);
    float A2 = aatt * gg[2], R2 = arel * gg[2];
    float A3 = aatt * gg[3], R3 = arel * gg[3];
    float v0 = fmaf(b1, A2, A3);
    float vm = fmaxf(fmaf(b1, R2, A3), fmaf(b2, A2, R3));
    float v2 = fmaf(b2, R2, R3);
    qq[0] = fmaf(s0, u0, v0);
    qq[1] = fmaxf(fmaf(s0, um, v0), fmaf(s1, u0, vm));
    qq[2] = fmax3f(fmaf(s0, u2, v0), fmaf(s1, um, vm), fmaf(s2, u0, v2));
    qq[3] = fmaxf(fmaf(s1, u2, vm), fmaf(s2, um, v2));
    qq[4] = fmaf(s2, u2, v2);
  };
  auto mk17 = [&](int qb, float* o17) {   // 4 quads -> 17-piece span-16 op
    float qa[5], qc[5], o9a[9], o9b[9];
    mkquad(qb + 0, qa); mkquad(qb + 1, qc);
    compose_im<5, 5>(o9a, qc, qa, b1_4, rat);
    mkquad(qb + 2, qa); mkquad(qb + 3, qc);
    compose_im<5, 5>(o9b, qc, qa, b1_4, rat);
    compose_im<9, 9>(o17, o9b, o9a, b1_8, rat);
  };

  float o33a[33], o33b[33], o65[65];
  {
    float o17a[17], o17b[17];
    mk17(0, o17a); mk17(4, o17b);
    compose_im<17, 17>(o33a, o17b, o17a, b1_16, rat);
    mk17(8, o17a); mk17(12, o17b);
    compose_im<17, 17>(o33b, o17b, o17a, b1_16, rat);
  }
  compose_im<33, 33>(o65, o33b, o33a, b1_32, rat);   // EXACT span-64 op

  half8* dst = ops64 + (size_t)(p * NCH + ch) * 9;
#pragma unroll
  for (int j8 = 0; j8 < 9; ++j8) {
    half8 hb;
#pragma unroll
    for (int e = 0; e < 8; ++e) {
      const int k = 8 * j8 + e;
      hb[e] = (k < 65) ? (half_t)o65[k] : (half_t)0.0f;
    }
    dst[j8] = hb;
  }
}

// Warm-up scan: lane l -> (ch = l&15, cpos = wv*4 + l>>4). Applies up to 128
// span-64 ops (exact 65-piece) ending at the chunk start; writes g_start.
// All hot state in NAMED vector/scalar SSA values — no arrays, no scratch.
__global__ __launch_bounds__(64, 1) void scanA_kernel(
    const half8* __restrict__ ops64,
    const float* __restrict__ p_att,
    const float* __restrict__ p_rel,
    float* __restrict__ g_start, int nthreads) {
  // XCD-chunked wg swizzle (512 wgs, %8==0): cpos-adjacent threads (which
  // share 15/16 of their op windows) colocate on one XCD's L2.
  const int nwg = gridDim.x;
  const int cpx = nwg >> 3;
  const int bidx = blockIdx.x;
  const int sb = (bidx & 7) * cpx + (bidx >> 3);
  const int tid = sb * 64 + (int)threadIdx.x;
  if (tid >= nthreads) return;
  const int l    = tid & 63;
  const int wv   = tid >> 6;
  const int ch   = l & 15;
  const int cpos = wv * 4 + (l >> 4);        // 0..2047

  const float L2E = 1.4426950408889634f;
  const float aatt = 1.0f - __builtin_exp2f(-L2E / (p_att[0] * 48000.0f));
  const float arel = 1.0f - __builtin_exp2f(-L2E / (p_rel[0] * 48000.0f));
  const float b1 = 1.0f - aatt, b2 = 1.0f - arel;
  const float rat = b2 / b1;

  // Slope ladder b1^(64-i) b2^i as 8 named f32x8 + 1 scalar (SSA, no array).
  f32x8 S0, S1, S2, S3, S4, S5, S6, S7;
  float S64;
  {
    const float b1_2 = b1 * b1, b1_4 = b1_2 * b1_2, b1_8 = b1_4 * b1_4;
    const float b1_16 = b1_8 * b1_8, b1_32 = b1_16 * b1_16;
    float pw = b1_32 * b1_32;   // b1^64
#define SA_FILL(v)                                                   \
  v[0] = pw; pw *= rat; v[1] = pw; pw *= rat; v[2] = pw; pw *= rat;  \
  v[3] = pw; pw *= rat; v[4] = pw; pw *= rat; v[5] = pw; pw *= rat;  \
  v[6] = pw; pw *= rat; v[7] = pw; pw *= rat;
    SA_FILL(S0) SA_FILL(S1) SA_FILL(S2) SA_FILL(S3)
    SA_FILL(S4) SA_FILL(S5) SA_FILL(S6) SA_FILL(S7)
    S64 = pw;   // b2^64
#undef SA_FILL
  }

  float g = 0.0f;

  const int navail = cpos * 8;
  const int nops = (navail < N_WARM_OPS) ? navail : N_WARM_OPS;  // even
  if (nops > 0) {
    const int p0 = cpos * 8 - nops;
    const half8* P = ops64 + (size_t)(p0 * NCH + ch) * 9;
    const size_t stride = (size_t)NCH * 9;      // half8 units per p step

    half8 a0, a1, a2, a3, a4, a5, a6, a7, a8;   // ping
    half8 n0, n1, n2, n3, n4, n5, n6, n7, n8;   // pong

#define SA_LD(pre, ptr)                                              \
  { const half8* q_ = (ptr);                                         \
    pre##0 = q_[0]; pre##1 = q_[1]; pre##2 = q_[2]; pre##3 = q_[3];  \
    pre##4 = q_[4]; pre##5 = q_[5]; pre##6 = q_[6]; pre##7 = q_[7];  \
    pre##8 = q_[8]; }
#define SA_APPLY(pre)                                                \
  { f32x8 c0 = __builtin_convertvector(pre##0, f32x8);               \
    f32x8 c1 = __builtin_convertvector(pre##1, f32x8);               \
    f32x8 c2 = __builtin_convertvector(pre##2, f32x8);               \
    f32x8 c3 = __builtin_convertvector(pre##3, f32x8);               \
    f32x8 c4 = __builtin_convertvector(pre##4, f32x8);               \
    f32x8 c5 = __builtin_convertvector(pre##5, f32x8);               \
    f32x8 c6 = __builtin_convertvector(pre##6, f32x8);               \
    f32x8 c7 = __builtin_convertvector(pre##7, f32x8);               \
    float c64 = (float)pre##8[0];                                    \
    f32x8 l0 = S0 * g + c0, l1 = S1 * g + c1;                        \
    f32x8 l2 = S2 * g + c2, l3 = S3 * g + c3;                        \
    f32x8 l4 = S4 * g + c4, l5 = S5 * g + c5;                        \
    f32x8 l6 = S6 * g + c6, l7 = S7 * g + c7;                        \
    f32x8 m01 = __builtin_elementwise_max(l0, l1);                   \
    f32x8 m23 = __builtin_elementwise_max(l2, l3);                   \
    f32x8 m45 = __builtin_elementwise_max(l4, l5);                   \
    f32x8 m67 = __builtin_elementwise_max(l6, l7);                   \
    f32x8 ma = __builtin_elementwise_max(m01, m23);                  \
    f32x8 mb = __builtin_elementwise_max(m45, m67);                  \
    f32x8 mm = __builtin_elementwise_max(ma, mb);                    \
    float r0 = fmaxf(fmaxf(mm[0], mm[1]), fmaxf(mm[2], mm[3]));      \
    float r1_ = fmaxf(fmaxf(mm[4], mm[5]), fmaxf(mm[6], mm[7]));     \
    g = fmaxf(fmaxf(r0, r1_), fmaf(S64, g, c64)); }

    SA_LD(a, P)
#pragma unroll 1
    for (int r = 0; r + 2 <= nops; r += 2) {
      SA_LD(n, P + (size_t)(r + 1) * stride)
      SA_APPLY(a)
      // r+2 == nops loads the op AT the chunk start: in-bounds, unused.
      SA_LD(a, P + (size_t)(r + 2) * stride)
      SA_APPLY(n)
    }
#undef SA_LD
#undef SA_APPLY
  }
  g_start[ch * CH_CHUNKS + cpos] = g;
}

// Output region: per chunk, 512-sample recurrence from g_start.
__global__ __launch_bounds__(256) void scanB_kernel(
    const float* __restrict__ audio,
    const float* __restrict__ g_start,
    const float* __restrict__ p_thr,
    const float* __restrict__ p_ratio,
    const float* __restrict__ p_att,
    const float* __restrict__ p_rel,
    const float* __restrict__ p_mk,
    float* __restrict__ out, int nchunks) {
  const int tid = blockIdx.x * 256 + (int)threadIdx.x;
  if (tid >= nchunks) return;
  const int ch = tid >> 11;
  const int t0 = (tid & 2047) * C_CHUNK;

  const float thr = p_thr[0];
  const float r1  = 1.0f - 1.0f / p_ratio[0];
  const float K   = 6.0205999132796239f * r1;
  const float Cc  = -thr * r1;
  const float L2E = 1.4426950408889634f;
  const float aatt = 1.0f - __builtin_exp2f(-L2E / (p_att[0] * 48000.0f));
  const float arel = 1.0f - __builtin_exp2f(-L2E / (p_rel[0] * 48000.0f));
  const float b1 = 1.0f - aatt, b2 = 1.0f - arel;
  const float EK  = 0.16609640474436813f;         // log2(10)/20
  const float emk = p_mk[0] * EK;

  float g = g_start[tid];
  const fvec4* Ap = (const fvec4*)(audio + (size_t)ch * T_LEN + t0);
  fvec4* Op = (fvec4*)(out + (size_t)ch * T_LEN + t0);
  const bool zfix = (t0 == 0);

  fvec4 a0[8], a1[8];
  auto lda = [&](fvec4 (&ab)[8], int b) {
#pragma unroll
    for (int i = 0; i < 8; ++i) ab[i] = Ap[8 * b + i];
  };
  auto emit = [&](const fvec4 (&ab)[8], int b, bool first) {
    fvec4 r[8];
#pragma unroll
    for (int s = 0; s < 32; ++s) {
      float x = ab[s >> 2][s & 3];
      float ax = fabsf(x) + 1e-8f;
      float grv = fmaxf(fmaf(K, __builtin_log2f(ax), Cc), 0.0f);
      if (first && s == 0 && zfix) grv = 0.0f;   // t==0: g stays 0
      float Aa = aatt * grv, Rr = arel * grv;    // off-chain
      g = fmaxf(fmaf(b1, g, Aa), fmaf(b2, g, Rr));   // 2-dep chain
      float mag = ax * __builtin_exp2f(fmaf(-EK, g, emk));
      float o = copysignf(mag, x);
      r[s >> 2][s & 3] = (x == 0.0f) ? 0.0f : o;
    }
#pragma unroll
    for (int i = 0; i < 8; ++i) Op[8 * b + i] = r[i];
  };

  const int NB = C_CHUNK / 32;   // 16
  lda(a0, 0);
#pragma unroll 1
  for (int b = 0; b < NB; b += 2) {
    lda(a1, b + 1);
    emit(a0, b, b == 0);
    const int bnx = (b + 2 < NB) ? b + 2 : NB - 1;
    lda(a0, bnx);
    emit(a1, b + 1, false);
  }
}

extern "C" void kernel_launch(void* const* d_in, const int* in_sizes, int n_in,
                              void* d_out, int out_size, void* d_ws, size_t ws_size,
                              hipStream_t stream) {
  const float* audio   = (const float*)d_in[0];
  const float* p_thr   = (const float*)d_in[1];
  const float* p_ratio = (const float*)d_in[2];
  const float* p_att   = (const float*)d_in[3];
  const float* p_rel   = (const float*)d_in[4];
  const float* p_mk    = (const float*)d_in[5];
  float* outp = (float*)d_out;

  const int n = in_sizes[0];           // 16 * 2^20
  const int nrec = n / 64;             // 262144 ops * 144 B = 37.75 MB
  const int nchunks = n / C_CHUNK;     // 32768

  half8* ops64   = (half8*)d_ws;                        // [0, 37.75 MB)
  float* g_start = (float*)((char*)d_ws + ((size_t)48 << 20));  // 128 KB

  pre64_kernel<<<(nrec + 255) / 256, 256, 0, stream>>>(
      audio, p_thr, p_ratio, p_att, p_rel, ops64, nrec);
  scanA_kernel<<<(nchunks + 63) / 64, 64, 0, stream>>>(
      ops64, p_att, p_rel, g_start, nchunks);
  scanB_kernel<<<(nchunks + 255) / 256, 256, 0, stream>>>(
      audio, g_start, p_thr, p_ratio, p_att, p_rel, p_mk, outp, nchunks);
}

// Round 15
// 176.015 us; speedup vs baseline: 6.4819x; 1.0234x over previous
//
#include <hip/hip_runtime.h>

// Dynamic range compressor via EXACT composed max-affine scan operators.
//   gr[t]  = max(20*log10(|x|+1e-8) - thr, 0)*(1-1/ratio)
//   g[0]=0; g[t] = (1-a)*g[t-1] + a*gr[t],  a = att if gr[t]>g[t-1] else rel
//   out[t] = sign(x)*(|x|+1e-8)*10^((mk - g[t])/20)
// 64-fold composition = EXACT 65-piece max-affine op (slopes b1^(64-i)b2^i).
// pre64 (span-64 ops, fp16 144B, layout [p][ch]) -> scanA (128 applies ->
// g_start) -> scanB (512-sample output region).
// Round 15 = round 14 with the macro-expansion bug fixed (deferred expansion
// via variadic wrappers; r14's SA_LD(AA,P) matched arg-count pre-expansion).
// r14 intent: scanB named-register rewrite (r13: VGPR=32 + WRITE 176MB>67MB
// = fvec4 arrays spilled); scanA depth-4 load rotation (27 loads in flight).
// NOTE: no <math.h> (glibc __MATHCALL collides with HIP intrinsics).

#define T_LEN   (1 << 20)
#define NCH     16
#define C_CHUNK 512
#define RECS_PER_CH (T_LEN / 64)      // 16384 span-64 ops per channel
#define CH_CHUNKS   (T_LEN / C_CHUNK) // 2048 chunks per channel
#define N_WARM_OPS  128               // W = 8192 samples

typedef _Float16 half_t;
typedef _Float16 half8 __attribute__((ext_vector_type(8)));
typedef float    fvec4 __attribute__((ext_vector_type(4)));
typedef float    f32x8 __attribute__((ext_vector_type(8)));

__device__ __forceinline__ float fmax3f(float a, float b, float c) {
  return fmaxf(fmaxf(a, b), c);
}

// dst = hi ∘ lo (hi after lo), i-major, slope updated incrementally. Exact.
template <int P, int Q>
__device__ __forceinline__ void compose_im(float* __restrict__ dst,
                                           const float* __restrict__ hi,
                                           const float* __restrict__ lo,
                                           float s, float rat) {
#pragma unroll
  for (int k = 0; k < P + Q - 1; ++k) dst[k] = -1e30f;
#pragma unroll
  for (int i = 0; i < P; ++i) {
#pragma unroll
    for (int j = 0; j < Q; ++j)
      dst[i + j] = fmaxf(dst[i + j], fmaf(s, lo[j], hi[i]));
    s *= rat;
  }
}

// One thread per 64-sample record: depth-first tree -> EXACT 65-piece op.
// Write 9 half8 (144 B) at TRANSPOSED index p*16+ch.
__global__ __launch_bounds__(256, 1) void pre64_kernel(
    const float* __restrict__ audio,
    const float* __restrict__ p_thr,
    const float* __restrict__ p_ratio,
    const float* __restrict__ p_att,
    const float* __restrict__ p_rel,
    half8* __restrict__ ops64, int nrec) {
  const int rec = blockIdx.x * 256 + (int)threadIdx.x;
  if (rec >= nrec) return;
  const int ch = rec >> 14;            // RECS_PER_CH = 16384
  const int p  = rec & 16383;

  const float thr = p_thr[0];
  const float r1  = 1.0f - 1.0f / p_ratio[0];
  const float K   = 6.0205999132796239f * r1;    // 20*log10(2)*r1
  const float Cc  = -thr * r1;
  const float L2E = 1.4426950408889634f;
  const float aatt = 1.0f - __builtin_exp2f(-L2E / (p_att[0] * 48000.0f));
  const float arel = 1.0f - __builtin_exp2f(-L2E / (p_rel[0] * 48000.0f));
  const float b1 = 1.0f - aatt, b2 = 1.0f - arel;
  const float s0 = b1 * b1, s1 = b1 * b2, s2 = b2 * b2;
  const float rat = b2 / b1;
  const float b1_4 = s0 * s0, b1_8 = b1_4 * b1_4, b1_16 = b1_8 * b1_8,
              b1_32 = b1_16 * b1_16;

  const fvec4* A4 = (const fvec4*)(audio) + (size_t)rec * 16;
  const bool zf = (p == 0);

  auto mkquad = [&](int b, float* qq) {
    fvec4 v = A4[b];
    float gg[4];
#pragma unroll
    for (int j = 0; j < 4; ++j)
      gg[j] = fmaxf(fmaf(K, __builtin_log2f(fabsf(v[j]) + 1e-8f), Cc), 0.0f);
    if (zf && b == 0) gg[0] = 0.0f;    // t==0: reference makes no update
    float A0 = aatt * gg[0], R0 = arel * gg[0];
    float A1 = aatt * gg[1], R1 = arel * gg[1];
    float u0 = fmaf(b1, A0, A1);
    float um = fmaxf(fmaf(b1, R0, A1), fmaf(b2, A0, R1));
    float u2 = fmaf(b2, R0, R1);
    float A2 = aatt * gg[2], R2 = arel * gg[2];
    float A3 = aatt * gg[3], R3 = arel * gg[3];
    float v0 = fmaf(b1, A2, A3);
    float vm = fmaxf(fmaf(b1, R2, A3), fmaf(b2, A2, R3));
    float v2 = fmaf(b2, R2, R3);
    qq[0] = fmaf(s0, u0, v0);
    qq[1] = fmaxf(fmaf(s0, um, v0), fmaf(s1, u0, vm));
    qq[2] = fmax3f(fmaf(s0, u2, v0), fmaf(s1, um, vm), fmaf(s2, u0, v2));
    qq[3] = fmaxf(fmaf(s1, u2, vm), fmaf(s2, um, v2));
    qq[4] = fmaf(s2, u2, v2);
  };
  auto mk17 = [&](int qb, float* o17) {   // 4 quads -> 17-piece span-16 op
    float qa[5], qc[5], o9a[9], o9b[9];
    mkquad(qb + 0, qa); mkquad(qb + 1, qc);
    compose_im<5, 5>(o9a, qc, qa, b1_4, rat);
    mkquad(qb + 2, qa); mkquad(qb + 3, qc);
    compose_im<5, 5>(o9b, qc, qa, b1_4, rat);
    compose_im<9, 9>(o17, o9b, o9a, b1_8, rat);
  };

  float o33a[33], o33b[33], o65[65];
  {
    float o17a[17], o17b[17];
    mk17(0, o17a); mk17(4, o17b);
    compose_im<17, 17>(o33a, o17b, o17a, b1_16, rat);
    mk17(8, o17a); mk17(12, o17b);
    compose_im<17, 17>(o33b, o17b, o17a, b1_16, rat);
  }
  compose_im<33, 33>(o65, o33b, o33a, b1_32, rat);   // EXACT span-64 op

  half8* dst = ops64 + (size_t)(p * NCH + ch) * 9;
#pragma unroll
  for (int j8 = 0; j8 < 9; ++j8) {
    half8 hb;
#pragma unroll
    for (int e = 0; e < 8; ++e) {
      const int k = 8 * j8 + e;
      hb[e] = (k < 65) ? (half_t)o65[k] : (half_t)0.0f;
    }
    dst[j8] = hb;
  }
}

// Warm-up scan: lane l -> (ch = l&15, cpos = wv*4 + l>>4). Applies up to 128
// span-64 ops ending at the chunk start; writes g_start. All hot state in
// NAMED vector/scalar SSA values; depth-4 load rotation (27 loads in flight).
__global__ __launch_bounds__(64, 1) void scanA_kernel(
    const half8* __restrict__ ops64,
    const float* __restrict__ p_att,
    const float* __restrict__ p_rel,
    float* __restrict__ g_start, int nthreads) {
  // XCD-chunked wg swizzle (512 wgs, %8==0): cpos-adjacent threads (which
  // share 15/16 of their op windows) colocate on one XCD's L2.
  const int nwg = gridDim.x;
  const int cpx = nwg >> 3;
  const int bidx = blockIdx.x;
  const int sb = (bidx & 7) * cpx + (bidx >> 3);
  const int tid = sb * 64 + (int)threadIdx.x;
  if (tid >= nthreads) return;
  const int l    = tid & 63;
  const int wv   = tid >> 6;
  const int ch   = l & 15;
  const int cpos = wv * 4 + (l >> 4);        // 0..2047

  const float L2E = 1.4426950408889634f;
  const float aatt = 1.0f - __builtin_exp2f(-L2E / (p_att[0] * 48000.0f));
  const float arel = 1.0f - __builtin_exp2f(-L2E / (p_rel[0] * 48000.0f));
  const float b1 = 1.0f - aatt, b2 = 1.0f - arel;
  const float rat = b2 / b1;

  // Slope ladder b1^(64-i) b2^i as 8 named f32x8 + 1 scalar (SSA, no array).
  f32x8 S0, S1, S2, S3, S4, S5, S6, S7;
  float S64;
  {
    const float b1_2 = b1 * b1, b1_4 = b1_2 * b1_2, b1_8 = b1_4 * b1_4;
    const float b1_16 = b1_8 * b1_8, b1_32 = b1_16 * b1_16;
    float pw = b1_32 * b1_32;   // b1^64
#define SA_FILL(v)                                                   \
  v[0] = pw; pw *= rat; v[1] = pw; pw *= rat; v[2] = pw; pw *= rat;  \
  v[3] = pw; pw *= rat; v[4] = pw; pw *= rat; v[5] = pw; pw *= rat;  \
  v[6] = pw; pw *= rat; v[7] = pw; pw *= rat;
    SA_FILL(S0) SA_FILL(S1) SA_FILL(S2) SA_FILL(S3)
    SA_FILL(S4) SA_FILL(S5) SA_FILL(S6) SA_FILL(S7)
    S64 = pw;   // b2^64
#undef SA_FILL
  }

  float g = 0.0f;

  const int navail = cpos * 8;
  const int nops = (navail < N_WARM_OPS) ? navail : N_WARM_OPS;  // %8 == 0
  if (nops > 0) {
    const int p0 = cpos * 8 - nops;
    const half8* P = ops64 + (size_t)(p0 * NCH + ch) * 9;
    const size_t stride = (size_t)NCH * 9;      // half8 units per p step

    half8 a0, a1, a2, a3, a4, a5, a6, a7, a8;   // rotation slot A
    half8 b0, b1_, b2_, b3, b4, b5, b6, b7, b8; // slot B
    half8 c0, c1, c2, c3, c4, c5, c6, c7, c8;   // slot C
    half8 d0, d1, d2, d3, d4, d5, d6, d7, d8;   // slot D

// Deferred-expansion wrappers: the slot-pack macro (AA/BB/CC/DD) must be
// expanded BEFORE the inner macro's arg-count check (r14 bug).
#define SA_LD(ptr, ...) SA_LD_I(ptr, __VA_ARGS__)
#define SA_LD_I(ptr, s0_, s1_, s2_, s3_, s4_, s5_, s6_, s7_, s8_)    \
  { const half8* q_ = (ptr);                                         \
    s0_ = q_[0]; s1_ = q_[1]; s2_ = q_[2]; s3_ = q_[3];              \
    s4_ = q_[4]; s5_ = q_[5]; s6_ = q_[6]; s7_ = q_[7]; s8_ = q_[8]; }
#define SA_AP(...) SA_AP_I(__VA_ARGS__)
#define SA_AP_I(s0_, s1_, s2_, s3_, s4_, s5_, s6_, s7_, s8_)         \
  { f32x8 c0_ = __builtin_convertvector(s0_, f32x8);                 \
    f32x8 c1_ = __builtin_convertvector(s1_, f32x8);                 \
    f32x8 c2_ = __builtin_convertvector(s2_, f32x8);                 \
    f32x8 c3_ = __builtin_convertvector(s3_, f32x8);                 \
    f32x8 c4_ = __builtin_convertvector(s4_, f32x8);                 \
    f32x8 c5_ = __builtin_convertvector(s5_, f32x8);                 \
    f32x8 c6_ = __builtin_convertvector(s6_, f32x8);                 \
    f32x8 c7_ = __builtin_convertvector(s7_, f32x8);                 \
    float c64_ = (float)s8_[0];                                      \
    f32x8 l0 = S0 * g + c0_, l1 = S1 * g + c1_;                      \
    f32x8 l2 = S2 * g + c2_, l3 = S3 * g + c3_;                      \
    f32x8 l4 = S4 * g + c4_, l5 = S5 * g + c5_;                      \
    f32x8 l6 = S6 * g + c6_, l7 = S7 * g + c7_;                      \
    f32x8 m01 = __builtin_elementwise_max(l0, l1);                   \
    f32x8 m23 = __builtin_elementwise_max(l2, l3);                   \
    f32x8 m45 = __builtin_elementwise_max(l4, l5);                   \
    f32x8 m67 = __builtin_elementwise_max(l6, l7);                   \
    f32x8 ma = __builtin_elementwise_max(m01, m23);                  \
    f32x8 mb = __builtin_elementwise_max(m45, m67);                  \
    f32x8 mm = __builtin_elementwise_max(ma, mb);                    \
    float r0_ = fmaxf(fmaxf(mm[0], mm[1]), fmaxf(mm[2], mm[3]));     \
    float r1x = fmaxf(fmaxf(mm[4], mm[5]), fmaxf(mm[6], mm[7]));     \
    g = fmaxf(fmaxf(r0_, r1x), fmaf(S64, g, c64_)); }
#define AA a0, a1, a2, a3, a4, a5, a6, a7, a8
#define BB b0, b1_, b2_, b3, b4, b5, b6, b7, b8
#define CC c0, c1, c2, c3, c4, c5, c6, c7, c8
#define DD d0, d1, d2, d3, d4, d5, d6, d7, d8

    SA_LD(P, AA)
    SA_LD(P + stride, BB)
    SA_LD(P + 2 * stride, CC)
#pragma unroll 1
    for (int r = 0; r + 4 <= nops; r += 4) {
      // overrun loads reach <= chunk-start op +2 (< RECS_PER_CH): unused.
      SA_LD(P + (size_t)(r + 3) * stride, DD)
      SA_AP(AA)
      SA_LD(P + (size_t)(r + 4) * stride, AA)
      SA_AP(BB)
      SA_LD(P + (size_t)(r + 5) * stride, BB)
      SA_AP(CC)
      SA_LD(P + (size_t)(r + 6) * stride, CC)
      SA_AP(DD)
    }
#undef SA_LD
#undef SA_LD_I
#undef SA_AP
#undef SA_AP_I
#undef AA
#undef BB
#undef CC
#undef DD
  }
  g_start[ch * CH_CHUNKS + cpos] = g;
}

// Output region: per chunk, 512-sample recurrence from g_start.
// NAMED fvec4 registers only (r13: arrays spilled -> 109MB scratch writes).
__global__ __launch_bounds__(256, 1) void scanB_kernel(
    const float* __restrict__ audio,
    const float* __restrict__ g_start,
    const float* __restrict__ p_thr,
    const float* __restrict__ p_ratio,
    const float* __restrict__ p_att,
    const float* __restrict__ p_rel,
    const float* __restrict__ p_mk,
    float* __restrict__ out, int nchunks) {
  const int tid = blockIdx.x * 256 + (int)threadIdx.x;
  if (tid >= nchunks) return;
  const int ch = tid >> 11;
  const int t0 = (tid & 2047) * C_CHUNK;

  const float thr = p_thr[0];
  const float r1  = 1.0f - 1.0f / p_ratio[0];
  const float K   = 6.0205999132796239f * r1;
  const float Cc  = -thr * r1;
  const float L2E = 1.4426950408889634f;
  const float aatt = 1.0f - __builtin_exp2f(-L2E / (p_att[0] * 48000.0f));
  const float arel = 1.0f - __builtin_exp2f(-L2E / (p_rel[0] * 48000.0f));
  const float b1 = 1.0f - aatt, b2 = 1.0f - arel;
  const float EK  = 0.16609640474436813f;         // log2(10)/20
  const float emk = p_mk[0] * EK;

  float g = g_start[tid];
  const fvec4* Ap = (const fvec4*)(audio + (size_t)ch * T_LEN + t0);
  fvec4* Op = (fvec4*)(out + (size_t)ch * T_LEN + t0);
  const bool zfix = (t0 == 0);

  auto emit4 = [&](fvec4 x4, bool fz) -> fvec4 {
    fvec4 rv;
#pragma unroll
    for (int j = 0; j < 4; ++j) {
      float x = x4[j];
      float ax = fabsf(x) + 1e-8f;
      float grv = fmaxf(fmaf(K, __builtin_log2f(ax), Cc), 0.0f);
      if (j == 0 && fz) grv = 0.0f;                 // t==0: g stays 0
      float Aa = aatt * grv, Rr = arel * grv;       // off-chain
      g = fmaxf(fmaf(b1, g, Aa), fmaf(b2, g, Rr));  // 2-dep chain
      float mag = ax * __builtin_exp2f(fmaf(-EK, g, emk));
      float o = copysignf(mag, x);
      rv[j] = (x == 0.0f) ? 0.0f : o;
    }
    return rv;
  };

  fvec4 c0, c1, c2, c3, c4, c5, c6, c7;   // current 32 samples
  fvec4 n0, n1, n2, n3, n4, n5, n6, n7;   // next 32 samples

#define SB_LD(b, ...) SB_LD_I(b, __VA_ARGS__)
#define SB_LD_I(b, p0_, p1_, p2_, p3_, p4_, p5_, p6_, p7_)           \
  { const fvec4* q_ = Ap + 8 * (b);                                  \
    p0_ = q_[0]; p1_ = q_[1]; p2_ = q_[2]; p3_ = q_[3];              \
    p4_ = q_[4]; p5_ = q_[5]; p6_ = q_[6]; p7_ = q_[7]; }
#define SB_EM(b, fz, ...) SB_EM_I(b, fz, __VA_ARGS__)
#define SB_EM_I(b, fz, p0_, p1_, p2_, p3_, p4_, p5_, p6_, p7_)       \
  { fvec4* o_ = Op + 8 * (b);                                        \
    o_[0] = emit4(p0_, fz);    o_[1] = emit4(p1_, false);            \
    o_[2] = emit4(p2_, false); o_[3] = emit4(p3_, false);            \
    o_[4] = emit4(p4_, false); o_[5] = emit4(p5_, false);            \
    o_[6] = emit4(p6_, false); o_[7] = emit4(p7_, false); }
#define CV c0, c1, c2, c3, c4, c5, c6, c7
#define NV n0, n1, n2, n3, n4, n5, n6, n7

  SB_LD(0, CV)
#pragma unroll 1
  for (int b = 0; b < 16; b += 2) {
    SB_LD(b + 1, NV)
    SB_EM(b, (b == 0) && zfix, CV)
    const int bnx = (b + 2 < 16) ? b + 2 : 15;   // clamp: no OOB at chan end
    SB_LD(bnx, CV)
    SB_EM(b + 1, false, NV)
  }
#undef SB_LD
#undef SB_LD_I
#undef SB_EM
#undef SB_EM_I
#undef CV
#undef NV
}

extern "C" void kernel_launch(void* const* d_in, const int* in_sizes, int n_in,
                              void* d_out, int out_size, void* d_ws, size_t ws_size,
                              hipStream_t stream) {
  const float* audio   = (const float*)d_in[0];
  const float* p_thr   = (const float*)d_in[1];
  const float* p_ratio = (const float*)d_in[2];
  const float* p_att   = (const float*)d_in[3];
  const float* p_rel   = (const float*)d_in[4];
  const float* p_mk    = (const float*)d_in[5];
  float* outp = (float*)d_out;

  const int n = in_sizes[0];           // 16 * 2^20
  const int nrec = n / 64;             // 262144 ops * 144 B = 37.75 MB
  const int nchunks = n / C_CHUNK;     // 32768

  half8* ops64   = (half8*)d_ws;                        // [0, 37.75 MB)
  float* g_start = (float*)((char*)d_ws + ((size_t)48 << 20));  // 128 KB

  pre64_kernel<<<(nrec + 255) / 256, 256, 0, stream>>>(
      audio, p_thr, p_ratio, p_att, p_rel, ops64, nrec);
  scanA_kernel<<<(nchunks + 63) / 64, 64, 0, stream>>>(
      ops64, p_att, p_rel, g_start, nchunks);
  scanB_kernel<<<(nchunks + 255) / 256, 256, 0, stream>>>(
      audio, g_start, p_thr, p_ratio, p_att, p_rel, p_mk, outp, nchunks);
}